// Round 10
// baseline (265.252 us; speedup 1.0000x reference)
//
#include <hip/hip_runtime.h>
#include <hip/hip_bf16.h>

#define B_  32
#define T_  2048
#define DH_ 1024
#define DS_ 1024
#define A_  512
#define M_  (B_ * T_)   // 65536

typedef __attribute__((ext_vector_type(8))) short bf16x8;
typedef __attribute__((ext_vector_type(4))) float f32x4;

__device__ __forceinline__ unsigned short f2bf(float f) {
    union { float f; unsigned u; } v; v.f = f;
    unsigned r = 0x7FFFu + ((v.u >> 16) & 1u);
    return (unsigned short)((v.u + r) >> 16);
}
__device__ __forceinline__ float fast_tanh(float x) {
    float cx = fminf(fmaxf(x, -9.f), 9.f);
    float e2 = __expf(2.f * cx);
    return (e2 - 1.f) / (e2 + 1.f);
}
__device__ __forceinline__ unsigned pack_bf2(float lo, float hi) {
    union { float f; unsigned u; } a, b;
    a.f = lo; b.f = hi;
    return __builtin_amdgcn_perm(b.u + 0x8000u, a.u + 0x8000u, 0x07060302u);
}

// ---- zero e [M_] ---------------------------------------------------------
__global__ void zero_e(float* __restrict__ e) {
    e[blockIdx.x * 256 + threadIdx.x] = 0.f;
}

// ---- U_t[a][k] = bf16(U_a[k][a]) -----------------------------------------
__global__ void prep_ut(const float* __restrict__ U, unsigned short* __restrict__ Ut) {
    int o = blockIdx.x * 256 + threadIdx.x;
    int a = o >> 10, k = o & (DH_ - 1);
    Ut[o] = f2bf(U[k * A_ + a]);
}

// ---- Ws[b][a] = s[b,:] . W_a[:,a]  (k-split 4-way + LDS reduce) ----------
__global__ void ws_gemv2(const float* __restrict__ s, const float* __restrict__ W,
                         float* __restrict__ Ws) {
    __shared__ float red[4][64];
    const int blk = blockIdx.x;
    const int b = blk >> 3, a0 = (blk & 7) * 64;
    const int tid = threadIdx.x;
    const int a = a0 + (tid & 63), kq = tid >> 6;
    const float* sp = s + b * DS_ + kq * 256;
    const float* wp = W + (size_t)(kq * 256) * A_ + a;
    float acc = 0.f;
#pragma unroll 8
    for (int k = 0; k < 256; ++k) acc += sp[k] * wp[(size_t)k * A_];
    red[kq][tid & 63] = acc;
    __syncthreads();
    if (tid < 64)
        Ws[b * A_ + a0 + tid] = red[0][tid] + red[1][tid] + red[2][tid] + red[3][tid];
}

// ---- main GEMM: BM=128, BN=128, BK=64, 4 waves (2x2, wave 64x64).
// A: reg-staged f32->bf16 perm-pack, T14 split (load early / pack+write
// late), 2-buffer, granule-swizzled ds_write (g^=r&7) -> conflict-free.
// B: global_load_lds w=16 with pre-swizzled source, 3-buffer counted
// vmcnt(4). One s_barrier per K-step (lgkmcnt folded in). 80 KB LDS ->
// 2 blocks/CU. 32 MFMA per barrier. XCD-chunked bid swizzle.
__global__ void __launch_bounds__(256, 2)
gemm_v3(const float* __restrict__ h,
        const unsigned short* __restrict__ Ut,
        const float* __restrict__ Ws, const float* __restrict__ va,
        float* __restrict__ e) {
    __shared__ unsigned short As[2][128][64];   // 32 KB
    __shared__ unsigned short Bs[3][128][64];   // 48 KB

    const int tid = threadIdx.x;
    // XCD-chunk swizzle: nwg = 2048, 256 wg/XCD; 4 tn-sharers same XCD
    const int bid0 = blockIdx.x;
    const int bid = (bid0 & 7) * 256 + (bid0 >> 3);
    const int tn = bid & 3, tm = bid >> 2;
    const int rowBase = tm * 128, nBase = tn * 128;

    const int lane = tid & 63;
    const int wid = tid >> 6;                   // 4 waves: 2(M) x 2(N)
    const int wm = wid >> 1, wn = wid & 1;      // wave tile 64x64
    const int lr = lane & 15, kg = lane >> 4;

    // A staging: thread covers row r = tid>>1, f32 cols (tid&1)*32 .. +31
    const int ar = tid >> 1;
    const int acf = (tid & 1) * 32;
    const int agb = (tid & 1) * 4;              // granule base (granule = 8 bf16)

    f32x4 acc[4][4];
#pragma unroll
    for (int i = 0; i < 4; ++i)
#pragma unroll
        for (int j = 0; j < 4; ++j) acc[i][j] = (f32x4){0.f, 0.f, 0.f, 0.f};

    auto stageB = [&](int buf, int tile) {      // 4 gls/thread (vmcnt unit)
        const int k0 = tile * 64;
#pragma unroll
        for (int j = 0; j < 4; ++j) {
            int byt = j * 4096 + tid * 16;      // byte off in 16 KB tile
            int r = byt >> 7;                   // row 0..127
            int g = ((byt >> 4) & 7) ^ (r & 7); // pre-swizzled source granule
            const unsigned short* gb = Ut + (size_t)(nBase + r) * DH_ + k0 + g * 8;
            __builtin_amdgcn_global_load_lds(
                (const __attribute__((address_space(1))) unsigned int*)gb,
                (__attribute__((address_space(3))) unsigned int*)(&Bs[buf][0][0] + (byt >> 1)),
                16, 0, 0);
        }
    };
    auto loadA = [&](float4* areg, int tile) {  // 8 dwordx4 -> regs
        const int k0 = tile * 64;
        const float* hp = h + (size_t)(rowBase + ar) * DH_ + k0 + acf;
#pragma unroll
        for (int j = 0; j < 8; ++j) areg[j] = *(const float4*)(hp + j * 4);
    };
    auto packwriteA = [&](const float4* areg, int buf) {
#pragma unroll
        for (int g4 = 0; g4 < 4; ++g4) {
            uint4 u;
            u.x = pack_bf2(areg[2 * g4].x, areg[2 * g4].y);
            u.y = pack_bf2(areg[2 * g4].z, areg[2 * g4].w);
            u.z = pack_bf2(areg[2 * g4 + 1].x, areg[2 * g4 + 1].y);
            u.w = pack_bf2(areg[2 * g4 + 1].z, areg[2 * g4 + 1].w);
            int gs = (agb + g4) ^ (ar & 7);     // swizzled granule
            *(uint4*)(&As[buf][ar][gs * 8]) = u;
        }
    };

    float4 areg[8];
    // prologue: B tiles 0,1 in flight; A tile 0 packed into As[0]
    stageB(0, 0);
    stageB(1, 1);
    loadA(areg, 0);
    packwriteA(areg, 0);

    const int NT = DH_ / 64;                    // 16 K-steps
#pragma unroll 1
    for (int t = 0; t < NT; ++t) {
        // B(t) landed (B(t+1) stays in flight); all ds_writes/reads drained
        asm volatile("s_waitcnt vmcnt(4) lgkmcnt(0)" ::: "memory");
        __builtin_amdgcn_s_barrier();
        __builtin_amdgcn_sched_barrier(0);

        if (t < NT - 2) stageB((t + 2) % 3, t + 2);
        if (t < NT - 1) loadA(areg, t + 1);     // T14: issue early

        const int abuf = t & 1;
        const unsigned short* Ab = &As[abuf][0][0];
        const unsigned short* Bb = &Bs[t % 3][0][0];

        bf16x8 af[2][4], bq[2][4];
#pragma unroll
        for (int kh = 0; kh < 2; ++kh) {
#pragma unroll
            for (int nf = 0; nf < 4; ++nf) {
                int rb = wn * 64 + nf * 16 + lr;
                bq[kh][nf] = *(const bf16x8*)(Bb + rb * 64 + (((kh * 4 + kg) ^ (rb & 7)) * 8));
            }
#pragma unroll
            for (int mf = 0; mf < 4; ++mf) {
                int ra = wm * 64 + mf * 16 + lr;
                af[kh][mf] = *(const bf16x8*)(Ab + ra * 64 + (((kh * 4 + kg) ^ (ra & 7)) * 8));
            }
        }

        __builtin_amdgcn_s_setprio(1);
#pragma unroll
        for (int kh = 0; kh < 2; ++kh)
#pragma unroll
            for (int mf = 0; mf < 4; ++mf)
#pragma unroll
                for (int nf = 0; nf < 4; ++nf)
                    acc[mf][nf] = __builtin_amdgcn_mfma_f32_16x16x32_bf16(
                        af[kh][mf], bq[kh][nf], acc[mf][nf], 0, 0, 0);
        __builtin_amdgcn_s_setprio(0);

        if (t < NT - 1) packwriteA(areg, abuf ^ 1);   // T14: write late
    }

    // epilogue: e[row] += sum_a tanh(acc + Ws[b][a]) * v[a]
    const int bIdx = rowBase >> 11;
    const float* WsRow = Ws + bIdx * A_;
    float wsv[4], vav[4];
#pragma unroll
    for (int nf = 0; nf < 4; ++nf) {
        int a = nBase + wn * 64 + nf * 16 + lr;
        wsv[nf] = WsRow[a];
        vav[nf] = va[a];
    }
#pragma unroll
    for (int mf = 0; mf < 4; ++mf) {
#pragma unroll
        for (int j = 0; j < 4; ++j) {
            float ssum = 0.f;
#pragma unroll
            for (int nf = 0; nf < 4; ++nf) {
                float x = acc[mf][nf][j] + wsv[nf];
                ssum += fast_tanh(x) * vav[nf];
            }
            ssum += __shfl_xor(ssum, 1);
            ssum += __shfl_xor(ssum, 2);
            ssum += __shfl_xor(ssum, 4);
            ssum += __shfl_xor(ssum, 8);
            if (lr == 0) {
                int row = rowBase + wm * 64 + mf * 16 + kg * 4 + j;
                atomicAdd(&e[row], ssum);
            }
        }
    }
}

// ---- fused softmax + context (f32 h, L3-warm): block = (b, dseg) ---------
__global__ void smax_ctx(const float* __restrict__ e, const float* __restrict__ h,
                         float* __restrict__ c) {
    __shared__ float al[T_];
    __shared__ float red[8];
    __shared__ float part[256];
    const int b = blockIdx.x >> 3, dseg = blockIdx.x & 7;
    const int tid = threadIdx.x;
    const float* ep = e + (size_t)b * T_;

    float4 v0 = ((const float4*)ep)[tid * 2];
    float4 v1 = ((const float4*)ep)[tid * 2 + 1];
    float m = fmaxf(fmaxf(fmaxf(v0.x, v0.y), fmaxf(v0.z, v0.w)),
                    fmaxf(fmaxf(v1.x, v1.y), fmaxf(v1.z, v1.w)));
#pragma unroll
    for (int off = 1; off < 64; off <<= 1) m = fmaxf(m, __shfl_xor(m, off));
    const int wv = tid >> 6;
    if ((tid & 63) == 0) red[wv] = m;
    __syncthreads();
    m = fmaxf(fmaxf(red[0], red[1]), fmaxf(red[2], red[3]));
    float e0 = __expf(v0.x - m), e1 = __expf(v0.y - m);
    float e2 = __expf(v0.z - m), e3 = __expf(v0.w - m);
    float e4 = __expf(v1.x - m), e5 = __expf(v1.y - m);
    float e6 = __expf(v1.z - m), e7 = __expf(v1.w - m);
    float ssum = e0 + e1 + e2 + e3 + e4 + e5 + e6 + e7;
#pragma unroll
    for (int off = 1; off < 64; off <<= 1) ssum += __shfl_xor(ssum, off);
    if ((tid & 63) == 0) red[4 + wv] = ssum;
    al[tid * 8 + 0] = e0; al[tid * 8 + 1] = e1;
    al[tid * 8 + 2] = e2; al[tid * 8 + 3] = e3;
    al[tid * 8 + 4] = e4; al[tid * 8 + 5] = e5;
    al[tid * 8 + 6] = e6; al[tid * 8 + 7] = e7;
    __syncthreads();
    const float inv = 1.f / (red[4] + red[5] + red[6] + red[7]);

    const int d = dseg * 128 + (tid & 127);
    const int th = tid >> 7;
    const float* hp = h + ((size_t)b * T_ + th) * DH_ + d;
    float acc = 0.f;
#pragma unroll 8
    for (int t = 0; t < T_ / 2; ++t)
        acc += al[2 * t + th] * hp[(size_t)(2 * t) * DH_];
    part[tid] = acc;
    __syncthreads();
    if (tid < 128)
        c[(size_t)b * DH_ + dseg * 128 + tid] = (part[tid] + part[tid + 128]) * inv;
}

extern "C" void kernel_launch(void* const* d_in, const int* in_sizes, int n_in,
                              void* d_out, int out_size, void* d_ws, size_t ws_size,
                              hipStream_t stream) {
    const float* s   = (const float*)d_in[0];
    const float* h   = (const float*)d_in[1];
    const float* W_a = (const float*)d_in[2];
    const float* U_a = (const float*)d_in[3];
    const float* v_a = (const float*)d_in[4];
    float* c = (float*)d_out;

    // workspace: e [65536 f32] | Ws [16384 f32] | Ut [524288 bf16]  (~1.3 MB)
    float* e  = (float*)d_ws;
    float* Ws = e + M_;
    unsigned short* Ut = (unsigned short*)(Ws + B_ * A_);

    zero_e<<<M_ / 256, 256, 0, stream>>>(e);
    prep_ut<<<(A_ * DH_) / 256, 256, 0, stream>>>(U_a, Ut);
    ws_gemv2<<<B_ * 8, 256, 0, stream>>>(s, W_a, Ws);
    gemm_v3<<<(M_ / 128) * (A_ / 128), 256, 0, stream>>>(h, Ut, Ws, v_a, e);
    smax_ctx<<<B_ * 8, 256, 0, stream>>>(e, h, c);
}

// Round 11
// 209.432 us; speedup vs baseline: 1.2665x; 1.2665x over previous
//
#include <hip/hip_runtime.h>
#include <hip/hip_bf16.h>

#define B_  32
#define T_  2048
#define DH_ 1024
#define DS_ 1024
#define A_  512
#define M_  (B_ * T_)   // 65536

typedef __attribute__((ext_vector_type(8))) short bf16x8;
typedef __attribute__((ext_vector_type(4))) float f32x4;

__device__ __forceinline__ unsigned short f2bf(float f) {
    union { float f; unsigned u; } v; v.f = f;
    unsigned r = 0x7FFFu + ((v.u >> 16) & 1u);
    return (unsigned short)((v.u + r) >> 16);
}
__device__ __forceinline__ float fast_tanh(float x) {
    float cx = fminf(fmaxf(x, -9.f), 9.f);
    float e2 = __expf(2.f * cx);
    return (e2 - 1.f) / (e2 + 1.f);
}
__device__ __forceinline__ unsigned pack_bf2(float lo, float hi) {
    union { float f; unsigned u; } a, b;
    a.f = lo; b.f = hi;
    return __builtin_amdgcn_perm(b.u + 0x8000u, a.u + 0x8000u, 0x07060302u);
}

// ---- zero e [M_] ---------------------------------------------------------
__global__ void zero_e(float* __restrict__ e) {
    e[blockIdx.x * 256 + threadIdx.x] = 0.f;
}

// ---- U_t[a][k] = bf16(U_a[k][a]) -----------------------------------------
__global__ void prep_ut(const float* __restrict__ U, unsigned short* __restrict__ Ut) {
    int o = blockIdx.x * 256 + threadIdx.x;
    int a = o >> 10, k = o & (DH_ - 1);
    Ut[o] = f2bf(U[k * A_ + a]);
}

// ---- Ws[b][a] = s[b,:] . W_a[:,a]  (k-split 4-way + LDS reduce) ----------
__global__ void ws_gemv2(const float* __restrict__ s, const float* __restrict__ W,
                         float* __restrict__ Ws) {
    __shared__ float red[4][64];
    const int blk = blockIdx.x;
    const int b = blk >> 3, a0 = (blk & 7) * 64;
    const int tid = threadIdx.x;
    const int a = a0 + (tid & 63), kq = tid >> 6;
    const float* sp = s + b * DS_ + kq * 256;
    const float* wp = W + (size_t)(kq * 256) * A_ + a;
    float acc = 0.f;
#pragma unroll 8
    for (int k = 0; k < 256; ++k) acc += sp[k] * wp[(size_t)k * A_];
    red[kq][tid & 63] = acc;
    __syncthreads();
    if (tid < 64)
        Ws[b * A_ + a0 + tid] = red[0][tid] + red[1][tid] + red[2][tid] + red[3][tid];
}

// ---- main GEMM: BM=256, BN=128, BK=32, 4 waves (2Mx2N, wave 128x64).
// A: f32 loads issued FIRST (oldest), pack+ds_write after MFMA — the
// compiler's auto vmcnt before the pack is then vmcnt(2), keeping the
// B gls pipeline in flight (R10 bug fixed). B: 3-buffer gls, pre-swizzled
// source. One raw s_barrier + lgkmcnt(0) per K-step; no vmcnt(0) in loop.
// 56 KB LDS -> 2 blocks/CU. Granule swizzle f(r)=(r>>1)&3 both paths.
__global__ void __launch_bounds__(256, 2)
gemm_v4(const float* __restrict__ h,
        const unsigned short* __restrict__ Ut,
        const float* __restrict__ Ws, const float* __restrict__ va,
        float* __restrict__ e) {
    __shared__ unsigned short As[2][256][32];   // 32 KB
    __shared__ unsigned short Bs[3][128][32];   // 24 KB

    const int tid = threadIdx.x;
    // XCD-chunk swizzle: nwg = 1024, 128 wg/XCD; 4 tn-sharers same XCD
    const int bid0 = blockIdx.x;
    const int bid = (bid0 & 7) * 128 + (bid0 >> 3);
    const int tn = bid & 3, tm = bid >> 2;
    const int rowBase = tm * 256, nBase = tn * 128;

    const int lane = tid & 63;
    const int wid = tid >> 6;                   // 4 waves: 2(M) x 2(N)
    const int wm = wid >> 1, wn = wid & 1;      // wave tile 128(m) x 64(n)
    const int lr = lane & 15, kg = lane >> 4;
    const int gsw = (kg ^ ((lr >> 1) & 3)) * 8; // lane-uniform read swizzle

    // A staging: 8 threads/row, rows j*32 + (tid>>3), f32 cols (tid&7)*4
    const int arj = tid >> 3;                   // row within 32-group
    const int acf = (tid & 7) * 4;              // f32 col
    const int ag4 = (tid & 7) >> 1;             // logical granule
    const int ahalf = (tid & 1) * 8;            // byte sub-offset in granule

    f32x4 acc[8][4];
#pragma unroll
    for (int i = 0; i < 8; ++i)
#pragma unroll
        for (int j = 0; j < 4; ++j) acc[i][j] = (f32x4){0.f, 0.f, 0.f, 0.f};

    auto stageB = [&](int buf, int tile) {      // 2 gls/thread
        const int k0 = tile * 32;
#pragma unroll
        for (int j = 0; j < 2; ++j) {
            int byt = j * 4096 + tid * 16;      // byte off in 8 KB tile
            int r = byt >> 6;                   // row 0..127
            int g = ((byt >> 4) & 3) ^ ((byt >> 7) & 3);
            const unsigned short* gb = Ut + (size_t)(nBase + r) * DH_ + k0 + g * 8;
            __builtin_amdgcn_global_load_lds(
                (const __attribute__((address_space(1))) unsigned int*)gb,
                (__attribute__((address_space(3))) unsigned int*)(&Bs[buf][0][0] + (byt >> 1)),
                16, 0, 0);
        }
    };
    auto loadA = [&](float4* areg, int tile) {  // 8 coalesced dwordx4
        const int k0 = tile * 32;
#pragma unroll
        for (int j = 0; j < 8; ++j) {
            int row = j * 32 + arj;
            areg[j] = *(const float4*)(h + (size_t)(rowBase + row) * DH_ + k0 + acf);
        }
    };
    auto packwriteA = [&](const float4* areg, int buf) {
#pragma unroll
        for (int j = 0; j < 8; ++j) {
            int row = j * 32 + arj;
            uint2 u;
            u.x = pack_bf2(areg[j].x, areg[j].y);
            u.y = pack_bf2(areg[j].z, areg[j].w);
            int gs = ag4 ^ ((row >> 1) & 3);
            *(uint2*)((char*)&As[buf][0][0] + row * 64 + gs * 16 + ahalf) = u;
        }
    };

    float4 areg[8];
    const int NT = DH_ / 32;                    // 32 K-steps

    // prologue: loadA(0) FIRST (oldest), then B tiles 0,1
    loadA(areg, 0);
    __builtin_amdgcn_sched_barrier(0);
    stageB(0, 0);
    stageB(1, 1);
    __builtin_amdgcn_sched_barrier(0);
    packwriteA(areg, 0);                        // auto-wait drains loadA only
    asm volatile("s_waitcnt vmcnt(2) lgkmcnt(0)" ::: "memory");  // B(0) landed
    __builtin_amdgcn_s_barrier();
    __builtin_amdgcn_sched_barrier(0);

#pragma unroll 1
    for (int t = 0; t < NT; ++t) {
        // entry: As[t&1], Bs[t%3] ready+visible; stageB(t+1) in flight
        if (t < NT - 1) loadA(areg, t + 1);     // issue FIRST -> oldest
        __builtin_amdgcn_sched_barrier(0);
        if (t < NT - 2) stageB((t + 2) % 3, t + 2);
        __builtin_amdgcn_sched_barrier(0);

        const unsigned short* Ab = &As[t & 1][0][0];
        const unsigned short* Bb = &Bs[t % 3][0][0];
        bf16x8 af[8], bq[4];
#pragma unroll
        for (int nf = 0; nf < 4; ++nf)
            bq[nf] = *(const bf16x8*)(Bb + (wn * 64 + nf * 16 + lr) * 32 + gsw);
#pragma unroll
        for (int mi = 0; mi < 8; ++mi)
            af[mi] = *(const bf16x8*)(Ab + (wm * 128 + mi * 16 + lr) * 32 + gsw);
        asm volatile("s_waitcnt lgkmcnt(0)" ::: "memory");
        __builtin_amdgcn_sched_barrier(0);

        __builtin_amdgcn_s_setprio(1);
#pragma unroll
        for (int mi = 0; mi < 8; ++mi)
#pragma unroll
            for (int nf = 0; nf < 4; ++nf)
                acc[mi][nf] = __builtin_amdgcn_mfma_f32_16x16x32_bf16(
                    af[mi], bq[nf], acc[mi][nf], 0, 0, 0);
        __builtin_amdgcn_s_setprio(0);
        __builtin_amdgcn_sched_barrier(0);

        // pack+write A(t+1): compiler auto-waits vmcnt(2) (stageB(t+2) flies)
        if (t < NT - 1) packwriteA(areg, (t + 1) & 1);
        asm volatile("s_waitcnt lgkmcnt(0)" ::: "memory");
        __builtin_amdgcn_s_barrier();
        __builtin_amdgcn_sched_barrier(0);
    }

    // epilogue: e[row] += sum_a tanh(acc + Ws[b][a]) * v[a]
    const int bIdx = rowBase >> 11;
    const float* WsRow = Ws + bIdx * A_;
    float wsv[4], vav[4];
#pragma unroll
    for (int nf = 0; nf < 4; ++nf) {
        int a = nBase + wn * 64 + nf * 16 + lr;
        wsv[nf] = WsRow[a];
        vav[nf] = va[a];
    }
#pragma unroll
    for (int mi = 0; mi < 8; ++mi) {
#pragma unroll
        for (int j = 0; j < 4; ++j) {
            float ssum = 0.f;
#pragma unroll
            for (int nf = 0; nf < 4; ++nf) {
                float x = acc[mi][nf][j] + wsv[nf];
                ssum += fast_tanh(x) * vav[nf];
            }
            ssum += __shfl_xor(ssum, 1);
            ssum += __shfl_xor(ssum, 2);
            ssum += __shfl_xor(ssum, 4);
            ssum += __shfl_xor(ssum, 8);
            if (lr == 0) {
                int row = rowBase + wm * 128 + mi * 16 + kg * 4 + j;
                atomicAdd(&e[row], ssum);
            }
        }
    }
}

// ---- fused softmax + context (f32 h, L3-warm): block = (b, dseg) ---------
__global__ void smax_ctx(const float* __restrict__ e, const float* __restrict__ h,
                         float* __restrict__ c) {
    __shared__ float al[T_];
    __shared__ float red[8];
    __shared__ float part[256];
    const int b = blockIdx.x >> 3, dseg = blockIdx.x & 7;
    const int tid = threadIdx.x;
    const float* ep = e + (size_t)b * T_;

    float4 v0 = ((const float4*)ep)[tid * 2];
    float4 v1 = ((const float4*)ep)[tid * 2 + 1];
    float m = fmaxf(fmaxf(fmaxf(v0.x, v0.y), fmaxf(v0.z, v0.w)),
                    fmaxf(fmaxf(v1.x, v1.y), fmaxf(v1.z, v1.w)));
#pragma unroll
    for (int off = 1; off < 64; off <<= 1) m = fmaxf(m, __shfl_xor(m, off));
    const int wv = tid >> 6;
    if ((tid & 63) == 0) red[wv] = m;
    __syncthreads();
    m = fmaxf(fmaxf(red[0], red[1]), fmaxf(red[2], red[3]));
    float e0 = __expf(v0.x - m), e1 = __expf(v0.y - m);
    float e2 = __expf(v0.z - m), e3 = __expf(v0.w - m);
    float e4 = __expf(v1.x - m), e5 = __expf(v1.y - m);
    float e6 = __expf(v1.z - m), e7 = __expf(v1.w - m);
    float ssum = e0 + e1 + e2 + e3 + e4 + e5 + e6 + e7;
#pragma unroll
    for (int off = 1; off < 64; off <<= 1) ssum += __shfl_xor(ssum, off);
    if ((tid & 63) == 0) red[4 + wv] = ssum;
    al[tid * 8 + 0] = e0; al[tid * 8 + 1] = e1;
    al[tid * 8 + 2] = e2; al[tid * 8 + 3] = e3;
    al[tid * 8 + 4] = e4; al[tid * 8 + 5] = e5;
    al[tid * 8 + 6] = e6; al[tid * 8 + 7] = e7;
    __syncthreads();
    const float inv = 1.f / (red[4] + red[5] + red[6] + red[7]);

    const int d = dseg * 128 + (tid & 127);
    const int th = tid >> 7;
    const float* hp = h + ((size_t)b * T_ + th) * DH_ + d;
    float acc = 0.f;
#pragma unroll 8
    for (int t = 0; t < T_ / 2; ++t)
        acc += al[2 * t + th] * hp[(size_t)(2 * t) * DH_];
    part[tid] = acc;
    __syncthreads();
    if (tid < 128)
        c[(size_t)b * DH_ + dseg * 128 + tid] = (part[tid] + part[tid + 128]) * inv;
}

extern "C" void kernel_launch(void* const* d_in, const int* in_sizes, int n_in,
                              void* d_out, int out_size, void* d_ws, size_t ws_size,
                              hipStream_t stream) {
    const float* s   = (const float*)d_in[0];
    const float* h   = (const float*)d_in[1];
    const float* W_a = (const float*)d_in[2];
    const float* U_a = (const float*)d_in[3];
    const float* v_a = (const float*)d_in[4];
    float* c = (float*)d_out;

    // workspace: e [65536 f32] | Ws [16384 f32] | Ut [524288 bf16]  (~1.3 MB)
    float* e  = (float*)d_ws;
    float* Ws = e + M_;
    unsigned short* Ut = (unsigned short*)(Ws + B_ * A_);

    zero_e<<<M_ / 256, 256, 0, stream>>>(e);
    prep_ut<<<(A_ * DH_) / 256, 256, 0, stream>>>(U_a, Ut);
    ws_gemv2<<<B_ * 8, 256, 0, stream>>>(s, W_a, Ws);
    gemm_v4<<<(M_ / 256) * (A_ / 128), 256, 0, stream>>>(h, Ut, Ws, v_a, e);
    smax_ctx<<<B_ * 8, 256, 0, stream>>>(e, h, c);
}